// Round 1
// baseline (336.774 us; speedup 1.0000x reference)
//
#include <hip/hip_runtime.h>

// CenterLoss: feature [B=128, D=128, T=2048] f32, label [B*T] int32, centers [C=64, D=128] f32
// out: [1 + C*D] f32  = (loss, difference)
//
// Identities (avoid transposed [N,D] walk):
//   S[c,d]     = sum of feat over rows with label c
//   loss       = (sumsq - 2*sum(S*ctr) + sum_c cnt[c]*||ctr_c||^2) / (N*D)
//   diff[c,d]  = (cnt[c]*ctr[c,d] - S[c,d]) / max(cnt[c],1)

#define NB 128
#define ND 128
#define NT 2048
#define NC 64

// ws layout (floats): [0,8192) S_g (c-major [C][D]); [8192] sumsq; [8208,8272) count (int)

__global__ __launch_bounds__(256) void k_zero(float* __restrict__ ws) {
    int i = blockIdx.x * 256 + threadIdx.x;
    if (i < 8272) ws[i] = 0.0f;
}

__global__ __launch_bounds__(256) void k_main(const float* __restrict__ feat,
                                              const int*  __restrict__ label,
                                              float* __restrict__ ws) {
    float* S_g     = ws;                 // [C*D]
    float* sumsq_g = ws + 8192;
    int*   cnt_g   = (int*)(ws + 8208);  // [C]

    // LDS partial S: logical [dp 0..63][c 0..63], stored swizzled at dp*64 + ((c+dp)&63)
    // -> scatter atomics: bank = (c+dp)%32, spread by random label c (avg ~2-way, free)
    // -> flush (lanes = consecutive dp, fixed c): banks distinct, global writes coalesced
    __shared__ float S[4096];
    __shared__ int   cnt[NC];
    __shared__ float red[256];

    const int tid = threadIdx.x;
    const int bid = blockIdx.x;
    const int tt = bid & 1;          // t-tile (2 of width 1024)
    const int dd = (bid >> 1) & 1;   // d-half (2 of width 64)
    const int b  = bid >> 2;
    const int t0 = tt * 1024;
    const int d0 = dd * 64;

    for (int i = tid; i < 4096; i += 256) S[i] = 0.0f;
    if (tid < NC) cnt[tid] = 0;
    __syncthreads();

    const int t = t0 + tid * 4;
    const int4 L = *(const int4*)(label + b * NT + t);
    const int l0 = L.x, l1 = L.y, l2 = L.z, l3 = L.w;

    if (dd == 0) {  // each (b,t-tile) counted exactly once
        atomicAdd(&cnt[l0], 1);
        atomicAdd(&cnt[l1], 1);
        atomicAdd(&cnt[l2], 1);
        atomicAdd(&cnt[l3], 1);
    }

    const float* fp = feat + ((size_t)b * ND + d0) * NT + t;
    float ss = 0.0f;

    for (int dj = 0; dj < 64; dj += 4) {
        // 4 independent float4 loads in flight per iteration
        float4 f0 = *(const float4*)(fp + (size_t)(dj + 0) * NT);
        float4 f1 = *(const float4*)(fp + (size_t)(dj + 1) * NT);
        float4 f2 = *(const float4*)(fp + (size_t)(dj + 2) * NT);
        float4 f3 = *(const float4*)(fp + (size_t)(dj + 3) * NT);

        {   int dp = dj + 0, base = dp * 64;
            ss += f0.x*f0.x + f0.y*f0.y + f0.z*f0.z + f0.w*f0.w;
            atomicAdd(&S[base + ((l0 + dp) & 63)], f0.x);
            atomicAdd(&S[base + ((l1 + dp) & 63)], f0.y);
            atomicAdd(&S[base + ((l2 + dp) & 63)], f0.z);
            atomicAdd(&S[base + ((l3 + dp) & 63)], f0.w);
        }
        {   int dp = dj + 1, base = dp * 64;
            ss += f1.x*f1.x + f1.y*f1.y + f1.z*f1.z + f1.w*f1.w;
            atomicAdd(&S[base + ((l0 + dp) & 63)], f1.x);
            atomicAdd(&S[base + ((l1 + dp) & 63)], f1.y);
            atomicAdd(&S[base + ((l2 + dp) & 63)], f1.z);
            atomicAdd(&S[base + ((l3 + dp) & 63)], f1.w);
        }
        {   int dp = dj + 2, base = dp * 64;
            ss += f2.x*f2.x + f2.y*f2.y + f2.z*f2.z + f2.w*f2.w;
            atomicAdd(&S[base + ((l0 + dp) & 63)], f2.x);
            atomicAdd(&S[base + ((l1 + dp) & 63)], f2.y);
            atomicAdd(&S[base + ((l2 + dp) & 63)], f2.z);
            atomicAdd(&S[base + ((l3 + dp) & 63)], f2.w);
        }
        {   int dp = dj + 3, base = dp * 64;
            ss += f3.x*f3.x + f3.y*f3.y + f3.z*f3.z + f3.w*f3.w;
            atomicAdd(&S[base + ((l0 + dp) & 63)], f3.x);
            atomicAdd(&S[base + ((l1 + dp) & 63)], f3.y);
            atomicAdd(&S[base + ((l2 + dp) & 63)], f3.z);
            atomicAdd(&S[base + ((l3 + dp) & 63)], f3.w);
        }
    }

    __syncthreads();

    // flush partial S to global (coalesced atomics: consecutive lanes -> consecutive d)
    for (int i = tid; i < 4096; i += 256) {
        int c = i >> 6, dp = i & 63;
        float v = S[dp * 64 + ((c + dp) & 63)];
        atomicAdd(&S_g[c * ND + d0 + dp], v);
    }
    if (dd == 0 && tid < NC) atomicAdd(&cnt_g[tid], cnt[tid]);

    // block-reduce sumsq, one global atomic per block
    red[tid] = ss;
    __syncthreads();
    for (int s = 128; s > 0; s >>= 1) {
        if (tid < s) red[tid] += red[tid + s];
        __syncthreads();
    }
    if (tid == 0) atomicAdd(sumsq_g, red[0]);
}

__global__ __launch_bounds__(256) void k_epi(const float* __restrict__ ws,
                                             const float* __restrict__ centers,
                                             float* __restrict__ out) {
    const float* S_g     = ws;
    const float* sumsq_g = ws + 8192;
    const int*   cnt_g   = (const int*)(ws + 8208);

    __shared__ float r1[256], r2[256];
    int tid = threadIdx.x;
    float cross = 0.0f, cc = 0.0f;
    for (int e = tid; e < NC * ND; e += 256) {
        int c = e >> 7;  // ND = 128
        float s   = S_g[e];
        float ctr = centers[e];
        float cn  = (float)cnt_g[c];
        float den = cn > 1.0f ? cn : 1.0f;
        out[1 + e] = (cn * ctr - s) / den;
        cross += s * ctr;
        cc    += cn * ctr * ctr;
    }
    r1[tid] = cross; r2[tid] = cc;
    __syncthreads();
    for (int s = 128; s > 0; s >>= 1) {
        if (tid < s) { r1[tid] += r1[tid + s]; r2[tid] += r2[tid + s]; }
        __syncthreads();
    }
    if (tid == 0) {
        float loss = (sumsq_g[0] - 2.0f * r1[0] + r2[0]) * (1.0f / 33554432.0f);
        out[0] = loss;
    }
}

extern "C" void kernel_launch(void* const* d_in, const int* in_sizes, int n_in,
                              void* d_out, int out_size, void* d_ws, size_t ws_size,
                              hipStream_t stream) {
    const float* feat    = (const float*)d_in[0];
    const int*   label   = (const int*)d_in[1];
    const float* centers = (const float*)d_in[2];
    float* out = (float*)d_out;
    float* ws  = (float*)d_ws;

    hipLaunchKernelGGL(k_zero, dim3(33),  dim3(256), 0, stream, ws);
    hipLaunchKernelGGL(k_main, dim3(512), dim3(256), 0, stream, feat, label, ws);
    hipLaunchKernelGGL(k_epi,  dim3(1),   dim3(256), 0, stream, ws, centers, out);
}

// Round 2
// 334.355 us; speedup vs baseline: 1.0072x; 1.0072x over previous
//
#include <hip/hip_runtime.h>

// CenterLoss: feature [B=128, D=128, T=2048] f32, label [B*T] int32, centers [C=64, D=128] f32
// out: [1 + C*D] f32  = (loss, difference)
//
// Identities:
//   S[c,d]     = sum of feat over rows with label c
//   loss       = (sumsq - 2*sum(S*ctr) + sum_c cnt[c]*||ctr_c||^2) / (N*D)
//   diff[c,d]  = (cnt[c]*ctr[c,d] - S[c,d]) / max(cnt[c],1)
//
// R1 lesson: 512 blocks / 4-deep load pipelining was latency-bound (436 GB/s, 21% occ).
// R2: 2048 blocks (8 d-slices x 2 t-tiles x 128 b), 8 float4 in flight, vgpr<=64 for
// 8 blocks/CU, x2-replicated swizzled LDS scatter target.

#define NB 128
#define ND 128
#define NT 2048
#define NC 64

// ws layout (floats): [0,8192) S_g ([C][D]); [8192] sumsq; [8208,8272) count (int)

__global__ __launch_bounds__(256) void k_zero(float* __restrict__ ws) {
    int i = blockIdx.x * 256 + threadIdx.x;
    if (i < 8272) ws[i] = 0.0f;
}

__global__ __launch_bounds__(256, 8) void k_main(const float* __restrict__ feat,
                                                 const int*  __restrict__ label,
                                                 float* __restrict__ ws) {
    float* S_g     = ws;                 // [C*D]
    float* sumsq_g = ws + 8192;
    int*   cnt_g   = (int*)(ws + 8208);  // [C]

    // Replicated+swizzled partial S: replica r=lane&1, logical [dp 0..15][c 0..63]
    // stored at (dp*2 + r)*64 + ((c+dp)&63).
    // Scatter instr (fixed dp): bank = (c+dp)%32, random c -> ~2 lanes/bank (free, m136);
    // same-address collision needs same label AND same parity (halved).
    __shared__ float S[2 * 16 * 64];
    __shared__ int   cnt[NC];
    __shared__ float red[256];

    const int tid = threadIdx.x;
    const int bid = blockIdx.x;
    const int ds = bid & 7;          // d-slice (8 of width 16)
    const int tt = (bid >> 3) & 1;   // t-tile (2 of width 1024)
    const int b  = bid >> 4;
    const int d0 = ds * 16;
    const int t0 = tt * 1024;
    const int rep = (tid & 1) * 64;  // replica offset in floats

    for (int i = tid; i < 2048; i += 256) S[i] = 0.0f;
    if (tid < NC) cnt[tid] = 0;
    __syncthreads();

    const int t = t0 + tid * 4;
    const int4 L = *(const int4*)(label + b * NT + t);
    const int l0 = L.x, l1 = L.y, l2 = L.z, l3 = L.w;

    if (ds == 0) {  // each (b,t-tile) counted exactly once
        atomicAdd(&cnt[l0], 1);
        atomicAdd(&cnt[l1], 1);
        atomicAdd(&cnt[l2], 1);
        atomicAdd(&cnt[l3], 1);
    }

    const float* fp = feat + ((size_t)b * ND + d0) * NT + t;
    float ss = 0.0f;

    #pragma unroll
    for (int dj = 0; dj < 16; dj += 8) {
        // 8 independent float4 loads in flight
        float4 f[8];
        #pragma unroll
        for (int u = 0; u < 8; ++u)
            f[u] = *(const float4*)(fp + (size_t)(dj + u) * NT);

        #pragma unroll
        for (int u = 0; u < 8; ++u) {
            const int dp = dj + u;
            const int base = dp * 128 + rep;  // (dp*2 + r)*64
            ss += f[u].x * f[u].x + f[u].y * f[u].y + f[u].z * f[u].z + f[u].w * f[u].w;
            atomicAdd(&S[base + ((l0 + dp) & 63)], f[u].x);
            atomicAdd(&S[base + ((l1 + dp) & 63)], f[u].y);
            atomicAdd(&S[base + ((l2 + dp) & 63)], f[u].z);
            atomicAdd(&S[base + ((l3 + dp) & 63)], f[u].w);
        }
    }

    __syncthreads();

    // flush: i enumerates (c, dp); sum both replicas; coalesced-ish global atomics
    for (int i = tid; i < 1024; i += 256) {
        int c = i >> 4, dp = i & 15;
        int sw = (c + dp) & 63;
        float v = S[dp * 128 + sw] + S[dp * 128 + 64 + sw];
        atomicAdd(&S_g[c * ND + d0 + dp], v);
    }
    if (ds == 0 && tid < NC) atomicAdd(&cnt_g[tid], cnt[tid]);

    // block-reduce sumsq, one global atomic per block
    red[tid] = ss;
    __syncthreads();
    for (int s = 128; s > 0; s >>= 1) {
        if (tid < s) red[tid] += red[tid + s];
        __syncthreads();
    }
    if (tid == 0) atomicAdd(sumsq_g, red[0]);
}

__global__ __launch_bounds__(256) void k_epi(const float* __restrict__ ws,
                                             const float* __restrict__ centers,
                                             float* __restrict__ out) {
    const float* S_g     = ws;
    const float* sumsq_g = ws + 8192;
    const int*   cnt_g   = (const int*)(ws + 8208);

    __shared__ float r1[256], r2[256];
    int tid = threadIdx.x;
    float cross = 0.0f, cc = 0.0f;
    for (int e = tid; e < NC * ND; e += 256) {
        int c = e >> 7;  // ND = 128
        float s   = S_g[e];
        float ctr = centers[e];
        float cn  = (float)cnt_g[c];
        float den = cn > 1.0f ? cn : 1.0f;
        out[1 + e] = (cn * ctr - s) / den;
        cross += s * ctr;
        cc    += cn * ctr * ctr;
    }
    r1[tid] = cross; r2[tid] = cc;
    __syncthreads();
    for (int s = 128; s > 0; s >>= 1) {
        if (tid < s) { r1[tid] += r1[tid + s]; r2[tid] += r2[tid + s]; }
        __syncthreads();
    }
    if (tid == 0) {
        float loss = (sumsq_g[0] - 2.0f * r1[0] + r2[0]) * (1.0f / 33554432.0f);
        out[0] = loss;
    }
}

extern "C" void kernel_launch(void* const* d_in, const int* in_sizes, int n_in,
                              void* d_out, int out_size, void* d_ws, size_t ws_size,
                              hipStream_t stream) {
    const float* feat    = (const float*)d_in[0];
    const int*   label   = (const int*)d_in[1];
    const float* centers = (const float*)d_in[2];
    float* out = (float*)d_out;
    float* ws  = (float*)d_ws;

    hipLaunchKernelGGL(k_zero, dim3(33),   dim3(256), 0, stream, ws);
    hipLaunchKernelGGL(k_main, dim3(2048), dim3(256), 0, stream, feat, label, ws);
    hipLaunchKernelGGL(k_epi,  dim3(1),    dim3(256), 0, stream, ws, centers, out);
}

// Round 3
// 332.891 us; speedup vs baseline: 1.0117x; 1.0044x over previous
//
#include <hip/hip_runtime.h>

// CenterLoss: feature [B=128, D=128, T=2048] f32, label [B*T] int32, centers [C=64, D=128] f32
// out: [1 + C*D] f32 = (loss, difference)
//
// R2 lesson: 2M global atomicAdds into 8KB serialized at the coherence point
// (WRITE_SIZE 33MB for 33KB of data; R1==R2 time despite occupancy change).
// R3: ZERO global atomics (per-block partials + reduce kernels) and
// global_load_lds DMA staging (in-flight bytes independent of VGPRs).

#define ND 128
#define NT 2048
#define NC 64
#define CH 128          // t per chunk
#define NCH (NT/CH)     // 16

// ws float offsets
#define OFF_P     0              // [1024 blocks][1024] partial S
#define OFF_SSP   1048576        // [1024] per-block sumsq
#define OFF_CNTP  1049600        // int [128 b][64 c]
#define OFF_CROSS 1057792        // [32]
#define OFF_CC    1057824        // [32]
#define OFF_SS    1057856        // [1]

// s_waitcnt vmcnt(0): vm[3:0]=0, exp=7, lgkm=0xF, vm[5:4]=0
#define WAITVM0() __builtin_amdgcn_s_waitcnt(0x0F70)

__device__ __forceinline__ void dma16(const float* g, float* l) {
    __builtin_amdgcn_global_load_lds(
        (const __attribute__((address_space(1))) void*)g,
        (__attribute__((address_space(3))) void*)l, 16, 0, 0);
}

__global__ __launch_bounds__(256, 6) void k_main(const float* __restrict__ feat,
                                                 const int*  __restrict__ label,
                                                 float* __restrict__ ws) {
    __shared__ float stg[2][16 * CH];  // 2 x 8 KB staging (wave-private slices)
    __shared__ float S[2048];          // replicated+swizzled partial S [dp16][rep2][c64]
    __shared__ float red[256];
    __shared__ int   cntS[NC];

    const int tid = threadIdx.x, bid = blockIdx.x;
    const int ds = bid & 7, b = bid >> 3;   // d-slice (16 rows), batch
    const int d0 = ds * 16;
    const int wave = tid >> 6, lane = tid & 63;
    const int rep = (tid & 1) * 64;

    for (int i = tid; i < 2048; i += 256) S[i] = 0.f;
    if (tid < NC) cntS[tid] = 0;
    __syncthreads();

    // DMA: wave w instr i (W=2w+i) stages LDS floats [W*256, W*256+256):
    // lane L -> lds W*1024B + L*16B = (dp = 2W + (L>>5), t = 4*(L&31))
    const size_t rowbase = (size_t)(b * ND + d0) * NT;
    const float* g0 = feat + rowbase + (size_t)(4 * wave     + (lane >> 5)) * NT + 4 * (lane & 31);
    const float* g1 = feat + rowbase + (size_t)(4 * wave + 2 + (lane >> 5)) * NT + 4 * (lane & 31);

    dma16(g0, &stg[0][(2 * wave) * 256]);
    dma16(g1, &stg[0][(2 * wave + 1) * 256]);

    const int* lp = label + b * NT + (tid & 15) * 8;
    int4 La = *(const int4*)(lp);
    int4 Lb = *(const int4*)(lp + 4);

    const int dp = tid >> 4;            // consume: wave-private rows 4w..4w+3
    const int t4 = (tid & 15) * 8;
    const int sbase = dp * 128 + rep;
    const bool docnt = (ds == 0) && (tid < 16);

    float ss = 0.f;

    for (int k = 0; k < NCH; ++k) {
        const int cur = k & 1;
        int4 Na, Nb;
        if (k + 1 < NCH) {
            const int nxt = cur ^ 1;
            dma16(g0 + (size_t)(k + 1) * CH, &stg[nxt][(2 * wave) * 256]);
            dma16(g1 + (size_t)(k + 1) * CH, &stg[nxt][(2 * wave + 1) * 256]);
            Na = *(const int4*)(lp + (k + 1) * CH);
            Nb = *(const int4*)(lp + (k + 1) * CH + 4);
        }
        WAITVM0();  // drain this wave's DMA (k and k+1 overlap in flight)

        const float4 fa = *(const float4*)&stg[cur][dp * CH + t4];
        const float4 fb = *(const float4*)&stg[cur][dp * CH + t4 + 4];

        ss += fa.x * fa.x + fa.y * fa.y + fa.z * fa.z + fa.w * fa.w
            + fb.x * fb.x + fb.y * fb.y + fb.z * fb.z + fb.w * fb.w;

        atomicAdd(&S[sbase + ((La.x + dp) & 63)], fa.x);
        atomicAdd(&S[sbase + ((La.y + dp) & 63)], fa.y);
        atomicAdd(&S[sbase + ((La.z + dp) & 63)], fa.z);
        atomicAdd(&S[sbase + ((La.w + dp) & 63)], fa.w);
        atomicAdd(&S[sbase + ((Lb.x + dp) & 63)], fb.x);
        atomicAdd(&S[sbase + ((Lb.y + dp) & 63)], fb.y);
        atomicAdd(&S[sbase + ((Lb.z + dp) & 63)], fb.z);
        atomicAdd(&S[sbase + ((Lb.w + dp) & 63)], fb.w);

        if (docnt) {  // labels counted once: ds==0 blocks, dp==0 threads
            atomicAdd(&cntS[La.x], 1); atomicAdd(&cntS[La.y], 1);
            atomicAdd(&cntS[La.z], 1); atomicAdd(&cntS[La.w], 1);
            atomicAdd(&cntS[Lb.x], 1); atomicAdd(&cntS[Lb.y], 1);
            atomicAdd(&cntS[Lb.z], 1); atomicAdd(&cntS[Lb.w], 1);
        }
        if (k + 1 < NCH) { La = Na; Lb = Nb; }
    }

    __syncthreads();

    // non-atomic flush of this block's partial S -> ws (coalesced stores)
    float* P = ws + OFF_P + (size_t)bid * 1024;
    for (int i = tid; i < 1024; i += 256) {
        int c = i >> 4, dpp = i & 15;
        int sw = (c + dpp) & 63;
        P[c * 16 + dpp] = S[dpp * 128 + sw] + S[dpp * 128 + 64 + sw];
    }
    if (ds == 0 && tid < NC) ((int*)(ws + OFF_CNTP))[b * NC + tid] = cntS[tid];

    red[tid] = ss;
    __syncthreads();
    for (int s = 128; s > 0; s >>= 1) {
        if (tid < s) red[tid] += red[tid + s];
        __syncthreads();
    }
    if (tid == 0) ws[OFF_SSP + bid] = red[0];
}

__global__ __launch_bounds__(256) void k_red(float* __restrict__ ws,
                                             const float* __restrict__ centers,
                                             float* __restrict__ out) {
    const int tid = threadIdx.x, bid = blockIdx.x;

    if (bid == 32) {  // reduce per-block sumsq partials
        __shared__ float r[256];
        float s = 0.f;
        for (int i = tid; i < 1024; i += 256) s += ws[OFF_SSP + i];
        r[tid] = s;
        __syncthreads();
        for (int k = 128; k > 0; k >>= 1) { if (tid < k) r[tid] += r[tid + k]; __syncthreads(); }
        if (tid == 0) ws[OFF_SS] = r[0];
        return;
    }

    // per-block (redundant) count reduce: cnt[c] = sum_b cntP[b][c]
    __shared__ int cred[256];
    __shared__ int cnt[NC];
    {
        const int c = tid & 63, part = tid >> 6;
        const int* cntP = (const int*)(ws + OFF_CNTP);
        int s = 0;
        for (int bb = part * 32; bb < part * 32 + 32; ++bb) s += cntP[bb * NC + c];
        cred[tid] = s;
    }
    __syncthreads();
    if (tid < NC) cnt[tid] = cred[tid] + cred[tid + 64] + cred[tid + 128] + cred[tid + 192];
    __syncthreads();

    const int e = bid * 256 + tid;                    // (c,d) element
    const int c = e >> 7, d = e & 127, dsl = d >> 4, dpp = d & 15;
    const float* Pp = ws + OFF_P + dsl * 1024 + c * 16 + dpp;
    float sum = 0.f;
    #pragma unroll 8
    for (int bb = 0; bb < 128; ++bb) sum += Pp[(size_t)bb * 8192];

    const float ctr = centers[e];
    const float cn  = (float)cnt[c];
    const float den = cn > 1.f ? cn : 1.f;
    out[1 + e] = (cn * ctr - sum) / den;

    __shared__ float r1[256], r2[256];
    r1[tid] = sum * ctr;
    r2[tid] = cn * ctr * ctr;
    __syncthreads();
    for (int k = 128; k > 0; k >>= 1) {
        if (tid < k) { r1[tid] += r1[tid + k]; r2[tid] += r2[tid + k]; }
        __syncthreads();
    }
    if (tid == 0) { ws[OFF_CROSS + bid] = r1[0]; ws[OFF_CC + bid] = r2[0]; }
}

__global__ __launch_bounds__(64) void k_epi(const float* __restrict__ ws,
                                            float* __restrict__ out) {
    int t = threadIdx.x;
    float cr = (t < 32) ? ws[OFF_CROSS + t] : 0.f;
    float cc = (t < 32) ? ws[OFF_CC + t] : 0.f;
    for (int o = 16; o > 0; o >>= 1) { cr += __shfl_down(cr, o); cc += __shfl_down(cc, o); }
    if (t == 0) out[0] = (ws[OFF_SS] - 2.f * cr + cc) * (1.f / 33554432.f);
}

extern "C" void kernel_launch(void* const* d_in, const int* in_sizes, int n_in,
                              void* d_out, int out_size, void* d_ws, size_t ws_size,
                              hipStream_t stream) {
    const float* feat    = (const float*)d_in[0];
    const int*   label   = (const int*)d_in[1];
    const float* centers = (const float*)d_in[2];
    float* out = (float*)d_out;
    float* ws  = (float*)d_ws;

    hipLaunchKernelGGL(k_main, dim3(1024), dim3(256), 0, stream, feat, label, ws);
    hipLaunchKernelGGL(k_red,  dim3(33),   dim3(256), 0, stream, ws, centers, out);
    hipLaunchKernelGGL(k_epi,  dim3(1),    dim3(64),  0, stream, ws, out);
}

// Round 5
// 212.442 us; speedup vs baseline: 1.5853x; 1.5670x over previous
//
#include <hip/hip_runtime.h>

// CenterLoss: feature [B=128, D=128, T=2048] f32, label [B*T] int32, centers [64,128] f32
// out: [1 + 64*128] f32 = (loss, difference)
//
// R1-R3: time pinned ~180us across 3 load structures; invariant = 33.5M LDS float atomics.
// R4 structure (counting-sort gather, zero hot-loop atomics) had an OOB bug:
//   sorted[] was 3072 but threads read tid*16+15 <= 4095 -> garbage offsets -> NaN in ss.
// R5: sorted[4096] fully initialized to zero-slot; asm memory clobbers around raw
// s_barrier so the compiler can't reorder LDS ops across it (s_barrier is IntrNoMem).

#define NT 2048
#define NC 64

// ws float offsets
#define OFF_P     0          // [256 blocks][64c * 64d] partial S
#define OFF_SSP   1048576    // [256] per-block sumsq
#define OFF_CNTP  1048832    // int [128 b][64 c]
#define OFF_CROSS 1057024    // [32]
#define OFF_CC    1057056    // [32]
#define OFF_SS    1057088    // [1]

// gfx9 s_waitcnt imm: vm[3:0]=bits3:0, exp=bits6:4, lgkm=bits11:8, vm[5:4]=bits15:14
#define WAIT_VM0()   __builtin_amdgcn_s_waitcnt(0x0F70)  // vmcnt(0), lgkm/exp free
#define WAIT_VM4()   __builtin_amdgcn_s_waitcnt(0x0F74)  // vmcnt(4)
#define WAIT_LGKM0() __builtin_amdgcn_s_waitcnt(0xC07F)  // lgkmcnt(0), vm/exp free
#define CFENCE()     __asm__ volatile("" ::: "memory")
#define BAR()        do { CFENCE(); __builtin_amdgcn_s_barrier(); CFENCE(); } while (0)

__device__ __forceinline__ void dma16(const float* g, float* l) {
    __builtin_amdgcn_global_load_lds(
        (const __attribute__((address_space(1))) void*)g,
        (__attribute__((address_space(3))) void*)l, 16, 0, 0);
}

__global__ __launch_bounds__(256) void k_main(const float* __restrict__ feat,
                                              const int*  __restrict__ label,
                                              float* __restrict__ ws) {
    __shared__ float rowbuf[2][2][2052];          // dbuf x 2 rows x (2048 + zero slot @2048)
    __shared__ unsigned short __attribute__((aligned(16))) sorted[4096];
    __shared__ float S_lds[64][33];               // [c][d mod 32], padded stride
    __shared__ float partial[2][256];
    __shared__ int cnt[NC], pstart[NC], ntc[NC], cursor[NC];

    const int tid = threadIdx.x, bid = blockIdx.x;
    const int dh = bid & 1, b = bid >> 1;         // d-half (64 rows), batch
    const int wave = tid >> 6, lane = tid & 63;

    // ---- init: ALL 4096 slots -> zero-slot byte offset (8192 = float idx 2048) ----
    for (int j = tid; j < 4096; j += 256) sorted[j] = (unsigned short)8192;
    if (tid < NC) { cnt[tid] = 0; cursor[tid] = 0; }
    if (tid < 4) rowbuf[tid >> 1][tid & 1][2048] = 0.0f;
    __syncthreads();

    // ---- histogram (one-time; 2048 lane-atomics) ----
    const int* lp = label + b * NT + tid * 8;
    const int4 La = *(const int4*)lp;
    const int4 Lb = *(const int4*)(lp + 4);
    atomicAdd(&cnt[La.x], 1); atomicAdd(&cnt[La.y], 1);
    atomicAdd(&cnt[La.z], 1); atomicAdd(&cnt[La.w], 1);
    atomicAdd(&cnt[Lb.x], 1); atomicAdd(&cnt[Lb.y], 1);
    atomicAdd(&cnt[Lb.z], 1); atomicAdd(&cnt[Lb.w], 1);
    __syncthreads();

    // ---- padded prefix (classes padded to x16 so every 16-slot group is single-class) ----
    if (tid == 0) {
        int pt = 0;
        for (int c = 0; c < NC; ++c) {
            int pl = (cnt[c] + 15) & ~15;
            pstart[c] = pt; ntc[c] = pl >> 4; pt += pl;   // pt <= 2048 + 64*15 = 3008
        }
    }
    __syncthreads();

    if (dh == 0 && tid < NC) ((int*)(ws + OFF_CNTP))[b * NC + tid] = cnt[tid];

    // ---- scatter: sorted[pos] = byte offset of t within an 8KB row ----
    {
        const int t0 = tid * 8;
        int l, p;
        l = La.x; p = pstart[l] + atomicAdd(&cursor[l], 1); sorted[p] = (unsigned short)((t0 + 0) * 4);
        l = La.y; p = pstart[l] + atomicAdd(&cursor[l], 1); sorted[p] = (unsigned short)((t0 + 1) * 4);
        l = La.z; p = pstart[l] + atomicAdd(&cursor[l], 1); sorted[p] = (unsigned short)((t0 + 2) * 4);
        l = La.w; p = pstart[l] + atomicAdd(&cursor[l], 1); sorted[p] = (unsigned short)((t0 + 3) * 4);
        l = Lb.x; p = pstart[l] + atomicAdd(&cursor[l], 1); sorted[p] = (unsigned short)((t0 + 4) * 4);
        l = Lb.y; p = pstart[l] + atomicAdd(&cursor[l], 1); sorted[p] = (unsigned short)((t0 + 5) * 4);
        l = Lb.z; p = pstart[l] + atomicAdd(&cursor[l], 1); sorted[p] = (unsigned short)((t0 + 6) * 4);
        l = Lb.w; p = pstart[l] + atomicAdd(&cursor[l], 1); sorted[p] = (unsigned short)((t0 + 7) * 4);
    }
    __syncthreads();

    // ---- this thread's 16 permuted byte-offsets -> VGPRs (reused for all 128 rows) ----
    int off[16];
    {
        const uint4 pk0 = *(const uint4*)&sorted[tid * 16];
        const uint4 pk1 = *(const uint4*)&sorted[tid * 16 + 8];
        off[0]  = pk0.x & 0xFFFF; off[1]  = pk0.x >> 16;
        off[2]  = pk0.y & 0xFFFF; off[3]  = pk0.y >> 16;
        off[4]  = pk0.z & 0xFFFF; off[5]  = pk0.z >> 16;
        off[6]  = pk0.w & 0xFFFF; off[7]  = pk0.w >> 16;
        off[8]  = pk1.x & 0xFFFF; off[9]  = pk1.x >> 16;
        off[10] = pk1.y & 0xFFFF; off[11] = pk1.y >> 16;
        off[12] = pk1.z & 0xFFFF; off[13] = pk1.z >> 16;
        off[14] = pk1.w & 0xFFFF; off[15] = pk1.w >> 16;
    }

    // ---- main loop over 32 d-pairs, double-buffered DMA staging ----
    const float* fbase = feat + ((size_t)b * 128 + dh * 64) * NT;
    float ss = 0.0f;

    {   // issue pair 0
        #pragma unroll
        for (int q = 0; q < 4; ++q) {
            int m = wave + 4 * q, r = m >> 3, p = m & 7;
            dma16(fbase + (size_t)r * NT + p * 256 + lane * 4, &rowbuf[0][r][p * 256]);
        }
    }

    for (int i = 0; i < 32; ++i) {
        const int buf = i & 1;
        if (i < 31) {
            const float* base = fbase + (size_t)(2 * (i + 1)) * NT;
            #pragma unroll
            for (int q = 0; q < 4; ++q) {
                int m = wave + 4 * q, r = m >> 3, p = m & 7;
                dma16(base + (size_t)r * NT + p * 256 + lane * 4, &rowbuf[buf ^ 1][r][p * 256]);
            }
            WAIT_VM4();   // pair i done (4 older); pair i+1 stays in flight
        } else {
            WAIT_VM0();
        }
        BAR();            // all waves' pair-i slices visible

        // gather + single-class register sums (ZERO atomics in hot loop)
        #pragma unroll
        for (int r = 0; r < 2; ++r) {
            const char* rb = (const char*)&rowbuf[buf][r][0];
            float s = 0.0f;
            #pragma unroll
            for (int j = 0; j < 16; ++j) {
                float v = *(const float*)(rb + off[j]);
                s += v; ss += v * v;
            }
            partial[r][tid] = s;
        }
        WAIT_LGKM0();
        BAR();            // partials visible

        // owners: 128 threads cover (c, row-parity)
        if (tid < 128) {
            const int c = tid & 63, r = tid >> 6;
            const int ft = pstart[c] >> 4, n = ntc[c];
            float s = 0.0f;
            for (int j = 0; j < n; ++j) s += partial[r][ft + j];
            S_lds[c][(2 * i + r) & 31] = s;
        }

        if ((i & 15) == 15) {  // flush 32-row tile, coalesced float4 stores
            WAIT_LGKM0();
            BAR();
            const int dbase = (i >> 4) << 5;
            const int c = tid >> 2, dj0 = (tid & 3) * 8;
            float4 v0, v1;
            v0.x = S_lds[c][dj0 + 0]; v0.y = S_lds[c][dj0 + 1];
            v0.z = S_lds[c][dj0 + 2]; v0.w = S_lds[c][dj0 + 3];
            v1.x = S_lds[c][dj0 + 4]; v1.y = S_lds[c][dj0 + 5];
            v1.z = S_lds[c][dj0 + 6]; v1.w = S_lds[c][dj0 + 7];
            float* dst = ws + OFF_P + (size_t)bid * 4096 + c * 64 + dbase + dj0;
            *(float4*)dst = v0;
            *(float4*)(dst + 4) = v1;
        }
    }

    // ---- block sumsq reduce ----
    __syncthreads();
    partial[0][tid] = ss;
    __syncthreads();
    for (int s = 128; s > 0; s >>= 1) {
        if (tid < s) partial[0][tid] += partial[0][tid + s];
        __syncthreads();
    }
    if (tid == 0) ws[OFF_SSP + bid] = partial[0][0];
}

__global__ __launch_bounds__(256) void k_red(float* __restrict__ ws,
                                             const float* __restrict__ centers,
                                             float* __restrict__ out) {
    const int tid = threadIdx.x, bid = blockIdx.x;

    if (bid == 32) {  // sumsq over 256 block partials
        __shared__ float r[256];
        r[tid] = ws[OFF_SSP + tid];
        __syncthreads();
        for (int k = 128; k > 0; k >>= 1) { if (tid < k) r[tid] += r[tid + k]; __syncthreads(); }
        if (tid == 0) ws[OFF_SS] = r[0];
        return;
    }

    // counts: cnt[c] = sum over 128 b
    __shared__ int cred[256];
    __shared__ int cnt[NC];
    {
        const int c = tid & 63, part = tid >> 6;
        const int* cntP = (const int*)(ws + OFF_CNTP);
        int s = 0;
        for (int bb = part * 32; bb < part * 32 + 32; ++bb) s += cntP[bb * NC + c];
        cred[tid] = s;
    }
    __syncthreads();
    if (tid < NC) cnt[tid] = cred[tid] + cred[tid + 64] + cred[tid + 128] + cred[tid + 192];
    __syncthreads();

    const int e = bid * 256 + tid;                 // (c,d)
    const int c = e >> 7, d = e & 127, dhh = d >> 6, dl = d & 63;
    const float* Pp = ws + OFF_P + (size_t)dhh * 4096 + c * 64 + dl;
    float sum = 0.0f;
    #pragma unroll 8
    for (int bb = 0; bb < 128; ++bb) sum += Pp[(size_t)bb * 8192];

    const float ctr = centers[e];
    const float cn  = (float)cnt[c];
    const float den = cn > 1.0f ? cn : 1.0f;
    out[1 + e] = (cn * ctr - sum) / den;

    __shared__ float r1[256], r2[256];
    r1[tid] = sum * ctr;
    r2[tid] = cn * ctr * ctr;
    __syncthreads();
    for (int k = 128; k > 0; k >>= 1) {
        if (tid < k) { r1[tid] += r1[tid + k]; r2[tid] += r2[tid + k]; }
        __syncthreads();
    }
    if (tid == 0) { ws[OFF_CROSS + bid] = r1[0]; ws[OFF_CC + bid] = r2[0]; }
}

__global__ __launch_bounds__(64) void k_epi(const float* __restrict__ ws,
                                            float* __restrict__ out) {
    int t = threadIdx.x;
    float cr = (t < 32) ? ws[OFF_CROSS + t] : 0.0f;
    float cc = (t < 32) ? ws[OFF_CC + t] : 0.0f;
    for (int o = 16; o > 0; o >>= 1) { cr += __shfl_down(cr, o); cc += __shfl_down(cc, o); }
    if (t == 0) out[0] = (ws[OFF_SS] - 2.0f * cr + cc) * (1.0f / 33554432.0f);
}

extern "C" void kernel_launch(void* const* d_in, const int* in_sizes, int n_in,
                              void* d_out, int out_size, void* d_ws, size_t ws_size,
                              hipStream_t stream) {
    const float* feat    = (const float*)d_in[0];
    const int*   label   = (const int*)d_in[1];
    const float* centers = (const float*)d_in[2];
    float* out = (float*)d_out;
    float* ws  = (float*)d_ws;

    hipLaunchKernelGGL(k_main, dim3(256), dim3(256), 0, stream, feat, label, ws);
    hipLaunchKernelGGL(k_red,  dim3(33),  dim3(256), 0, stream, ws, centers, out);
    hipLaunchKernelGGL(k_epi,  dim3(1),   dim3(64),  0, stream, ws, out);
}